// Round 6
// baseline (456.674 us; speedup 1.0000x reference)
//
#include <hip/hip_runtime.h>

#define SCALE 0.35355339059327379f   // 8^-0.5
#define RSQRT2 0.70710678118654752f

// ws layout (float offsets)
#define QT_SZ   (68*68*64)           // padded transposed q image: [xp][yp][ic]
#define WT_SZ   (64*64*132)          // [oc][ic][kh][12] (11 used + 1 pad)
#define QT_OFF  0
#define KT_OFF  (QT_OFF + QT_SZ)
#define WQT_OFF (KT_OFF + QT_SZ)
#define WKT_OFF (WQT_OFF + WT_SZ)
#define QD_OFF  (WKT_OFF + WT_SZ)    // [oc][il] 64*64
#define KD_OFF  (QD_OFF + 4096)
#define VP_OFF  (KD_OFF + 4096)      // Vpart [yg][x][ch] 8*64*64
#define VR_OFF  (VP_OFF + 8*64*64)   // Vrow  [ch][jl] 64*64

// ---------------- K1: 1x1 conv (q,k -> transposed padded imgs; v -> row-mean partials)
//                  + weight transposes for K2 ----------------
__global__ __launch_bounds__(192) void k1(const float* __restrict__ f,
                                          const float* __restrict__ w_qkv,
                                          const float* __restrict__ wq,
                                          const float* __restrict__ wk,
                                          float* __restrict__ ws)
{
    extern __shared__ float sm[];
    const int b = blockIdx.x, t = threadIdx.x;
    if (b < 512) {
        // compute block: x row, yg = group of 8 y's
        const int x = b >> 3, yg = b & 7;
        const int w = t >> 6, lane = t & 63;   // wave w: 0=q,1=k,2=v ; lane = oc
        float* fl = sm;           // [64][12] f slab (8 y per ic, padded pitch 12)
        float* wt = sm + 768;     // [64 ic][193] transposed w_qkv (pitch 193)
        if (t < 128) {
            const int ic = t >> 1, part = t & 1;
            *(float4*)&fl[ic*12 + part*4] =
                *(const float4*)(f + ic*4096 + x*64 + yg*8 + part*4);
        }
        #pragma unroll
        for (int j = 0; j < 16; ++j) {
            const int idx = t + 192*j;          // float4 index in [0,3072)
            float4 v = *(const float4*)(w_qkv + 4*idx);
            const int oc = idx >> 4;            // (4*idx)/64
            const int ic0 = (4*idx) & 63;
            wt[(ic0+0)*193 + oc] = v.x;
            wt[(ic0+1)*193 + oc] = v.y;
            wt[(ic0+2)*193 + oc] = v.z;
            wt[(ic0+3)*193 + oc] = v.w;
        }
        __syncthreads();
        float acc[8] = {0.f,0.f,0.f,0.f,0.f,0.f,0.f,0.f};
        #pragma unroll 8
        for (int ic = 0; ic < 64; ++ic) {
            const float wv = wt[ic*193 + w*64 + lane];
            const float4 a = *(const float4*)&fl[ic*12];
            const float4 c = *(const float4*)&fl[ic*12 + 4];
            acc[0] = fmaf(wv, a.x, acc[0]);
            acc[1] = fmaf(wv, a.y, acc[1]);
            acc[2] = fmaf(wv, a.z, acc[2]);
            acc[3] = fmaf(wv, a.w, acc[3]);
            acc[4] = fmaf(wv, c.x, acc[4]);
            acc[5] = fmaf(wv, c.y, acc[5]);
            acc[6] = fmaf(wv, c.z, acc[6]);
            acc[7] = fmaf(wv, c.w, acc[7]);
        }
        if (w < 2) {
            float* img = (w == 0) ? (ws + QT_OFF) : (ws + KT_OFF);
            const int rowb = (x + 2) * 68;
            #pragma unroll
            for (int j = 0; j < 8; ++j)
                img[(rowb + yg*8 + j + 2)*64 + lane] = acc[j];
            if (yg == 0) { img[(rowb+0)*64+lane] = 0.f; img[(rowb+1)*64+lane] = 0.f; }
            if (yg == 7) { img[(rowb+66)*64+lane] = 0.f; img[(rowb+67)*64+lane] = 0.f; }
            if (x < 4) {  // zero pad rows xp in {0,1,66,67}; yg splits the 68 cols
                const int xp = (x < 2) ? x : 64 + x;
                for (int yp = yg*9; yp < yg*9 + 9; ++yp)
                    if (yp < 68) img[(xp*68 + yp)*64 + lane] = 0.f;
            }
        } else {
            const float s = acc[0]+acc[1]+acc[2]+acc[3]+acc[4]+acc[5]+acc[6]+acc[7];
            (ws + VP_OFF)[(yg*64 + x)*64 + lane] = s * 0.015625f;   // /64 row-mean partial
        }
    } else {
        // weight transpose blocks: wq/wk [oc][ic][kh][kw] -> [oc][ic][kh][12]
        const int b2 = b - 512;
        const int type = b2 >> 6, oc = b2 & 63;
        const float* wsrc = type ? wk : wq;
        float* wdst = type ? (ws + WKT_OFF) : (ws + WQT_OFF);
        float* wl = sm;   // 7744 floats, [ic][121]
        #pragma unroll
        for (int j = 0; j < 11; ++j) {
            const int idx = t + 192*j;
            if (idx < 1936)
                *(float4*)&wl[4*idx] = *(const float4*)(wsrc + oc*7744 + 4*idx);
        }
        __syncthreads();
        for (int p = t; p < 704; p += 192) {   // 64 ic x 11 kh
            const int ic = p / 11, kh = p % 11;
            const float* src = &wl[ic*121 + kh*11];
            float* dst = &wdst[(oc*64 + ic)*132 + kh*12];
            #pragma unroll
            for (int kw = 0; kw < 11; ++kw) dst[kw] = src[kw];
        }
    }
}

// ---------------- K2: 11x11 stride-8 pad-2 conv + bias + exact GELU (blocks 0..255)
//                  + independent Vpart->Vrow reduce blocks (256..319) ----------------
__global__ __launch_bounds__(256) void k2(const float* __restrict__ ws_qT,
                                          const float* __restrict__ ws_kT,
                                          const float* __restrict__ ws_wqT,
                                          const float* __restrict__ ws_wkT,
                                          const float* __restrict__ bq,
                                          const float* __restrict__ bk,
                                          float* __restrict__ qd,
                                          float* __restrict__ kd,
                                          const float* __restrict__ Vpart,
                                          float* __restrict__ Vrow)
{
    __shared__ float patch[64*223];   // [64 ic][pitch 223] (223 odd -> 2-way aliasing only)
    const int b = blockIdx.x;
    const int t = threadIdx.x;

    if (b >= 256) {
        // ---- Vrow reduce block: jl = b-256, lane = ch (coalesced loads) ----
        if (t < 64) {
            const int jl = b - 256;
            float s = 0.f;
            #pragma unroll
            for (int yg = 0; yg < 8; ++yg)
                s += Vpart[(yg*64 + jl)*64 + t];
            Vrow[t*64 + jl] = s;    // [ch][jl]
        }
        return;
    }

    const int type = b >> 7, ox = (b >> 4) & 7, ocg = (b >> 1) & 7, oyh = b & 1;
    const float* img  = type ? ws_kT : ws_qT;
    const float* wT   = type ? ws_wkT : ws_wqT;
    const float* bias = type ? bk : bq;
    float* outp = type ? kd : qd;
    const int ocp = t >> 6, lane = t & 63;

    const int oc0 = ocg*8 + ocp*2, oc1 = oc0 + 1;
    const float* w0b = wT + (oc0*64 + lane)*132;
    const float* w1b = wT + (oc1*64 + lane)*132;
    float acc0[4] = {0.f,0.f,0.f,0.f};
    float acc1[4] = {0.f,0.f,0.f,0.f};

#define KH_BODY(khl, khg)                                                        \
    {                                                                            \
        const float4 a0 = *(const float4*)(w0b + (khg)*12);                      \
        const float4 b0 = *(const float4*)(w0b + (khg)*12 + 4);                  \
        const float4 c0 = *(const float4*)(w0b + (khg)*12 + 8);                  \
        const float4 a1 = *(const float4*)(w1b + (khg)*12);                      \
        const float4 b1 = *(const float4*)(w1b + (khg)*12 + 4);                  \
        const float4 c1 = *(const float4*)(w1b + (khg)*12 + 8);                  \
        const float* prow = &patch[lane*223 + (khl)*37];                         \
        _Pragma("unroll")                                                        \
        for (int oy = 0; oy < 4; ++oy) {                                         \
            const float* pr = prow + oy*8;                                       \
            acc0[oy] = fmaf(a0.x, pr[0], acc0[oy]);                              \
            acc1[oy] = fmaf(a1.x, pr[0], acc1[oy]);                              \
            acc0[oy] = fmaf(a0.y, pr[1], acc0[oy]);                              \
            acc1[oy] = fmaf(a1.y, pr[1], acc1[oy]);                              \
            acc0[oy] = fmaf(a0.z, pr[2], acc0[oy]);                              \
            acc1[oy] = fmaf(a1.z, pr[2], acc1[oy]);                              \
            acc0[oy] = fmaf(a0.w, pr[3], acc0[oy]);                              \
            acc1[oy] = fmaf(a1.w, pr[3], acc1[oy]);                              \
            acc0[oy] = fmaf(b0.x, pr[4], acc0[oy]);                              \
            acc1[oy] = fmaf(b1.x, pr[4], acc1[oy]);                              \
            acc0[oy] = fmaf(b0.y, pr[5], acc0[oy]);                              \
            acc1[oy] = fmaf(b1.y, pr[5], acc1[oy]);                              \
            acc0[oy] = fmaf(b0.z, pr[6], acc0[oy]);                              \
            acc1[oy] = fmaf(b1.z, pr[6], acc1[oy]);                              \
            acc0[oy] = fmaf(b0.w, pr[7], acc0[oy]);                              \
            acc1[oy] = fmaf(b1.w, pr[7], acc1[oy]);                              \
            acc0[oy] = fmaf(c0.x, pr[8], acc0[oy]);                              \
            acc1[oy] = fmaf(c1.x, pr[8], acc1[oy]);                              \
            acc0[oy] = fmaf(c0.y, pr[9], acc0[oy]);                              \
            acc1[oy] = fmaf(c1.y, pr[9], acc1[oy]);                              \
            acc0[oy] = fmaf(c0.z, pr[10], acc0[oy]);                             \
            acc1[oy] = fmaf(c1.z, pr[10], acc1[oy]);                             \
        }                                                                        \
    }

    // ---- chunk 0: kh 0..5 ----
    for (int kh = 0; kh < 6; ++kh) {
        const int xrow = (ox*8 + kh) * 68;
        for (int yl = ocp; yl < 35; yl += 4)
            patch[lane*223 + kh*37 + yl] = img[(xrow + oyh*32 + yl)*64 + lane];
    }
    __syncthreads();
    #pragma unroll
    for (int kh = 0; kh < 6; ++kh) KH_BODY(kh, kh)
    __syncthreads();
    // ---- chunk 1: kh 6..10 ----
    for (int kh = 0; kh < 5; ++kh) {
        const int xrow = (ox*8 + 6 + kh) * 68;
        for (int yl = ocp; yl < 35; yl += 4)
            patch[lane*223 + kh*37 + yl] = img[(xrow + oyh*32 + yl)*64 + lane];
    }
    __syncthreads();
    #pragma unroll
    for (int kh = 0; kh < 5; ++kh) KH_BODY(kh, kh + 6)
#undef KH_BODY

    #pragma unroll
    for (int j = 0; j < 4; ++j) {
        float v0 = acc0[j], v1 = acc1[j];
        #pragma unroll
        for (int m = 1; m < 64; m <<= 1) {
            v0 += __shfl_xor(v0, m, 64);
            v1 += __shfl_xor(v1, m, 64);
        }
        acc0[j] = v0; acc1[j] = v1;
    }
    if (lane == 0) {
        const float b0 = bias[oc0], b1 = bias[oc1];
        #pragma unroll
        for (int j = 0; j < 4; ++j) {
            const int il = ox*8 + oyh*4 + j;
            const float v0 = acc0[j] + b0;
            const float v1 = acc1[j] + b1;
            outp[oc0*64 + il] = 0.5f*v0*(1.0f + erff(v0*RSQRT2));
            outp[oc1*64 + il] = 0.5f*v1*(1.0f + erff(v1*RSQRT2));
        }
    }
}

// ---------------- K3: dots + softmax + PV + broadcast store ----------------
// grid 64 (i = low-res query index), 512 threads: wave = head h, lane = jl.
__global__ __launch_bounds__(512) void k3(const float* __restrict__ qd,
                                          const float* __restrict__ kd,
                                          const float* __restrict__ Vrow,
                                          float* __restrict__ out)
{
    __shared__ float vrow[64*65];   // [ch][jl], pitch 65
    const int x = blockIdx.x, t = threadIdx.x;
    for (int idx = t; idx < 4096; idx += 512)
        vrow[(idx >> 6)*65 + (idx & 63)] = Vrow[idx];
    __syncthreads();
    const int h = t >> 6, lane = t & 63;
    float d = 0.f;
    #pragma unroll
    for (int c = 0; c < 8; ++c)
        d = fmaf(qd[(h*8 + c)*64 + x], kd[(h*8 + c)*64 + lane], d);
    d *= SCALE;
    float m = d;
    #pragma unroll
    for (int mm = 1; mm < 64; mm <<= 1) m = fmaxf(m, __shfl_xor(m, mm, 64));
    const float e = __expf(d - m);
    float ssum = e;
    #pragma unroll
    for (int mm = 1; mm < 64; mm <<= 1) ssum += __shfl_xor(ssum, mm, 64);
    const float p = e / ssum;
    #pragma unroll
    for (int c = 0; c < 8; ++c) {
        float r = p * vrow[(h*8 + c)*65 + lane];
        #pragma unroll
        for (int mm = 1; mm < 64; mm <<= 1) r += __shfl_xor(r, mm, 64);
        out[(h*8 + c)*4096 + x*64 + lane] = r;
    }
}

extern "C" void kernel_launch(void* const* d_in, const int* in_sizes, int n_in,
                              void* d_out, int out_size, void* d_ws, size_t ws_size,
                              hipStream_t stream) {
    const float* f     = (const float*)d_in[0];
    const float* w_qkv = (const float*)d_in[1];
    const float* wq    = (const float*)d_in[2];
    const float* bq    = (const float*)d_in[3];
    const float* wk    = (const float*)d_in[4];
    const float* bk    = (const float*)d_in[5];
    float* out = (float*)d_out;
    float* ws  = (float*)d_ws;

    k1<<<640, 192, 13120*4, stream>>>(f, w_qkv, wq, wk, ws);
    // ---- ATTRIBUTION: k2 launched 20x (idempotent). t_k2 = (dur - 54.0)/19. ----
    for (int rep = 0; rep < 20; ++rep) {
        k2<<<320, 256, 0, stream>>>(ws + QT_OFF, ws + KT_OFF,
                                    ws + WQT_OFF, ws + WKT_OFF,
                                    bq, bk, ws + QD_OFF, ws + KD_OFF,
                                    ws + VP_OFF, ws + VR_OFF);
    }
    k3<<<64, 512, 0, stream>>>(ws + QD_OFF, ws + KD_OFF, ws + VR_OFF, out);
}

// Round 7
// 27.932 us; speedup vs baseline: 16.3498x; 16.3498x over previous
//
#include <hip/hip_runtime.h>

#define SCALE 0.35355339059327379f   // 8^-0.5
#define RSQRT2 0.70710678118654752f

// ws layout (float offsets)
#define PL      4624                 // 68*68 padded plane
#define QP_OFF  0                    // qP[64 oc][68][68]
#define KP_OFF  (64*PL)              // 295936
#define PART_OFF (2*64*PL)           // part[256 pid][64 oc][64 il]  (pid = type*128+ic*2+khh)
#define VP_OFF  (PART_OFF + 256*4096)
#define QD_OFF  (VP_OFF + 4*4096)    // qd[oc][il]
#define KD_OFF  (QD_OFF + 4096)
#define VR_OFF  (KD_OFF + 4096)      // Vrow[jl][ch]

// ---------------- K1: 1x1 qkv conv -> planar padded q/k planes + V row-mean partials ----
// grid 128: (x = b>>1, yh = b&1), 384 thr = 6 waves: (type q/k/v) x (y-oct), lane = oc.
__global__ __launch_bounds__(384) void k1(const float* __restrict__ f,
                                          const float* __restrict__ w_qkv,
                                          float* __restrict__ ws)
{
    __shared__ float sm[14656];      // wt[64][193] @0 ; fl[64][36] @12352
    const int b = blockIdx.x, t = threadIdx.x;
    const int x = b >> 1, yh = b & 1;
    float* wt = sm;
    float* fl = sm + 12352;

    // zero pad borders: block (x,0) -> qP plane x ; (x,1) -> kP plane x
    {
        float* plane = ws + (yh ? KP_OFF : QP_OFF) + x*PL;
        for (int j = t; j < 528; j += 384) {
            int idx;
            if (j < 272) {
                const int rp = j / 68, c = j % 68;
                const int row = (rp < 2) ? rp : rp + 64;
                idx = row*68 + c;
            } else {
                const int jj = j - 272;
                const int cp = jj >> 6, r2 = (jj & 63) + 2;
                const int col = (cp < 2) ? cp : cp + 64;
                idx = r2*68 + col;
            }
            plane[idx] = 0.f;
        }
    }
    // stage w_qkv transposed: wt[ic][3*64 oc]
    #pragma unroll
    for (int j = 0; j < 8; ++j) {
        const int idx = t + 384*j;   // float4 idx in [0,3072)
        const float4 v = *(const float4*)(w_qkv + 4*idx);
        const int oc = idx >> 4, ic0 = (4*idx) & 63;
        wt[(ic0+0)*193 + oc] = v.x;
        wt[(ic0+1)*193 + oc] = v.y;
        wt[(ic0+2)*193 + oc] = v.z;
        wt[(ic0+3)*193 + oc] = v.w;
    }
    // stage f slab [64 ic][32 y]
    for (int i = t; i < 512; i += 384) {
        const int ic = i >> 3, p = i & 7;
        *(float4*)&fl[ic*36 + p*4] = *(const float4*)(f + ic*4096 + x*64 + yh*32 + p*4);
    }
    __syncthreads();

    const int w = t >> 6, lane = t & 63;
    const int type = w >> 1, yoct = w & 1;
    float acc[16];
    #pragma unroll
    for (int j = 0; j < 16; ++j) acc[j] = 0.f;
    #pragma unroll 4
    for (int ic = 0; ic < 64; ++ic) {
        const float wv = wt[ic*193 + type*64 + lane];
        const float4 p0 = *(const float4*)&fl[ic*36 + yoct*16];
        const float4 p1 = *(const float4*)&fl[ic*36 + yoct*16 + 4];
        const float4 p2 = *(const float4*)&fl[ic*36 + yoct*16 + 8];
        const float4 p3 = *(const float4*)&fl[ic*36 + yoct*16 + 12];
        acc[0]  = fmaf(wv, p0.x, acc[0]);  acc[1]  = fmaf(wv, p0.y, acc[1]);
        acc[2]  = fmaf(wv, p0.z, acc[2]);  acc[3]  = fmaf(wv, p0.w, acc[3]);
        acc[4]  = fmaf(wv, p1.x, acc[4]);  acc[5]  = fmaf(wv, p1.y, acc[5]);
        acc[6]  = fmaf(wv, p1.z, acc[6]);  acc[7]  = fmaf(wv, p1.w, acc[7]);
        acc[8]  = fmaf(wv, p2.x, acc[8]);  acc[9]  = fmaf(wv, p2.y, acc[9]);
        acc[10] = fmaf(wv, p2.z, acc[10]); acc[11] = fmaf(wv, p2.w, acc[11]);
        acc[12] = fmaf(wv, p3.x, acc[12]); acc[13] = fmaf(wv, p3.y, acc[13]);
        acc[14] = fmaf(wv, p3.z, acc[14]); acc[15] = fmaf(wv, p3.w, acc[15]);
    }
    if (type < 2) {
        // planar store: plane[oc=lane], row x+2, cols yh*32+yoct*16+2 .. +16 (8B-aligned)
        float* plane = ws + (type ? KP_OFF : QP_OFF) + lane*PL;
        const int base = (x + 2)*68 + yh*32 + yoct*16 + 2;
        #pragma unroll
        for (int j = 0; j < 8; ++j)
            *(float2*)(plane + base + 2*j) = make_float2(acc[2*j], acc[2*j+1]);
    } else {
        float s = 0.f;
        #pragma unroll
        for (int j = 0; j < 16; ++j) s += acc[j];
        (ws + VP_OFF)[(yh*2 + yoct)*4096 + x*64 + lane] = s * 0.015625f;  // /64 partial
    }
}

// ---------------- K2: 11x11 s8 conv as K-split GEMM. grid 256: (type, ic, khh).
// 512 thr, lane = il (output pos), wave = oc-eighth. No LDS, no barriers.
// Plane window -> registers (L1-shared across waves); weights -> wave-uniform scalar loads.
__global__ __launch_bounds__(512) void k2(const float* __restrict__ ws_qP,
                                          const float* __restrict__ ws_kP,
                                          const float* __restrict__ wq,
                                          const float* __restrict__ wk,
                                          float* __restrict__ part)
{
    const int b = blockIdx.x, t = threadIdx.x;
    const int type = b >> 7, ic = (b >> 1) & 63, khh = b & 1;
    const int kh0 = khh ? 6 : 0, nkh = khh ? 5 : 6;
    const float* plane = (type ? ws_kP : ws_qP) + ic*PL;
    const float* wsrc  = (type ? wk : wq) + ic*121 + kh0*11;
    const int lane = t & 63;
    const int oc0 = __builtin_amdgcn_readfirstlane(t >> 6) * 8;   // wave-uniform
    const int ox = lane >> 3, oy = lane & 7;

    float acc[8] = {0.f,0.f,0.f,0.f,0.f,0.f,0.f,0.f};
    #pragma unroll
    for (int khl = 0; khl < 6; ++khl) {
        if (khl < nkh) {
            const int xp = ox*8 + kh0 + khl;
            const float* prow = plane + xp*68 + oy*8;     // 16B-aligned
            const float4 r0 = *(const float4*)(prow);
            const float4 r1 = *(const float4*)(prow + 4);
            const float4 r2 = *(const float4*)(prow + 8);
            const float pr[12] = {r0.x,r0.y,r0.z,r0.w, r1.x,r1.y,r1.z,r1.w,
                                  r2.x,r2.y,r2.z,r2.w};
            const float* wrow = wsrc + khl*11;
            #pragma unroll
            for (int kw = 0; kw < 11; ++kw) {
                const float pv = pr[kw];
                #pragma unroll
                for (int j = 0; j < 8; ++j) {
                    const float wgt = wrow[(oc0 + j)*7744 + kw];  // uniform -> s_load
                    acc[j] = fmaf(wgt, pv, acc[j]);
                }
            }
        }
    }
    // partial store: part[b][oc][il]   (pid == b by construction)
    float* pp = part + (size_t)b*4096 + lane;
    #pragma unroll
    for (int j = 0; j < 8; ++j) pp[(oc0 + j)*64] = acc[j];
}

// ---------------- K2R: reduce 128 K-partials per output + bias + exact GELU; Vrow finish.
// grid 128: (type, oc), 256 thr.
__global__ __launch_bounds__(256) void k2r(const float* __restrict__ part,
                                           const float* __restrict__ Vpart,
                                           const float* __restrict__ bq,
                                           const float* __restrict__ bk,
                                           float* __restrict__ qd,
                                           float* __restrict__ kd,
                                           float* __restrict__ Vrow)
{
    __shared__ float red[4][64];
    const int b = blockIdx.x, t = threadIdx.x;
    const int type = b >> 6, oc = b & 63;
    const int il = t & 63, q4 = t >> 6;
    float s = 0.f;
    #pragma unroll 8
    for (int p = q4*32; p < q4*32 + 32; ++p)
        s += part[(size_t)(type*128 + p)*4096 + oc*64 + il];
    red[q4][il] = s;
    if (type == 0 && q4 == 1) {       // Vrow: jl = oc, ch = il (independent work)
        float v = 0.f;
        #pragma unroll
        for (int p = 0; p < 4; ++p) v += Vpart[p*4096 + oc*64 + il];
        Vrow[oc*64 + il] = v;
    }
    __syncthreads();
    if (t < 64) {
        const float tot = red[0][t] + red[1][t] + red[2][t] + red[3][t];
        const float v = tot + (type ? bk[oc] : bq[oc]);
        (type ? kd : qd)[oc*64 + t] = 0.5f*v*(1.0f + erff(v*RSQRT2));
    }
}

// ---------------- K3: dots + softmax + PV + broadcast store ----------------
// grid 64 (x = image row), 512 thr: wave = head, lane = jl.
__global__ __launch_bounds__(512) void k3(const float* __restrict__ qd,
                                          const float* __restrict__ kd,
                                          const float* __restrict__ VrowG,
                                          float* __restrict__ out)
{
    __shared__ float vrow[64*65];     // [ch][jl], pitch 65
    const int x = blockIdx.x, t = threadIdx.x;
    for (int idx = t; idx < 4096; idx += 512) {
        const int jl = idx >> 6, ch = idx & 63;
        vrow[ch*65 + jl] = VrowG[idx];
    }
    __syncthreads();
    const int h = t >> 6, lane = t & 63;
    float d = 0.f;
    #pragma unroll
    for (int c = 0; c < 8; ++c)
        d = fmaf(qd[(h*8 + c)*64 + x], kd[(h*8 + c)*64 + lane], d);
    d *= SCALE;
    float m = d;
    #pragma unroll
    for (int mm = 1; mm < 64; mm <<= 1) m = fmaxf(m, __shfl_xor(m, mm, 64));
    const float e = __expf(d - m);
    float ssum = e;
    #pragma unroll
    for (int mm = 1; mm < 64; mm <<= 1) ssum += __shfl_xor(ssum, mm, 64);
    const float p = e / ssum;
    #pragma unroll
    for (int c = 0; c < 8; ++c) {
        float r = p * vrow[(h*8 + c)*65 + lane];
        #pragma unroll
        for (int mm = 1; mm < 64; mm <<= 1) r += __shfl_xor(r, mm, 64);
        out[(h*8 + c)*4096 + x*64 + lane] = r;
    }
}

extern "C" void kernel_launch(void* const* d_in, const int* in_sizes, int n_in,
                              void* d_out, int out_size, void* d_ws, size_t ws_size,
                              hipStream_t stream) {
    const float* f     = (const float*)d_in[0];
    const float* w_qkv = (const float*)d_in[1];
    const float* wq    = (const float*)d_in[2];
    const float* bq    = (const float*)d_in[3];
    const float* wk    = (const float*)d_in[4];
    const float* bk    = (const float*)d_in[5];
    float* out = (float*)d_out;
    float* ws  = (float*)d_ws;

    k1<<<128, 384, 0, stream>>>(f, w_qkv, ws);
    k2<<<256, 512, 0, stream>>>(ws + QP_OFF, ws + KP_OFF, wq, wk, ws + PART_OFF);
    k2r<<<128, 256, 0, stream>>>(ws + PART_OFF, ws + VP_OFF, bq, bk,
                                 ws + QD_OFF, ws + KD_OFF, ws + VR_OFF);
    k3<<<64, 512, 0, stream>>>(ws + QD_OFF, ws + KD_OFF, ws + VR_OFF, out);
}